// Round 8
// baseline (562.651 us; speedup 1.0000x reference)
//
#include <hip/hip_runtime.h>
#include <hip/hip_bf16.h>

// Problem constants (B=4, S=2048, H=2048, E=8, K=2)
#define T_TOK 8192
#define H_DIM 2048
#define NE 8
#define NT (H_DIM / 64)

typedef float f32x4 __attribute__((ext_vector_type(4)));
typedef short s16x8 __attribute__((ext_vector_type(8)));

typedef __attribute__((address_space(3))) unsigned int lds_uint;
typedef __attribute__((address_space(1))) const unsigned int glob_uint;

static __device__ __forceinline__ void async_ld16(const void* g, void* l) {
    // 64 lanes x 16B: global per-lane address -> LDS (wave-uniform base + lane*16)
    __builtin_amdgcn_global_load_lds((glob_uint*)g, (lds_uint*)l, 16, 0, 0);
}

static __device__ __forceinline__ unsigned short f32_to_bf16(float f) {
    unsigned int u = __builtin_bit_cast(unsigned int, f);
    unsigned int r = (u + 0x7FFFu + ((u >> 16) & 1u)) >> 16;
    return (unsigned short)r;
}

// ---------------------------------------------------------------------------
// Kernel 1: convert W fp32 -> bf16, zero expert counters. (R0-exact; ~77 us
// at ~5.2 TB/s ~= its 402 MB roofline. R6 proved in-GEMM fusion loses.)
// ---------------------------------------------------------------------------
__global__ __launch_bounds__(256) void prep_kernel(
        const float* __restrict__ w, unsigned short* __restrict__ wb,
        int* __restrict__ cnt) {
    const long g = (long)blockIdx.x * 256 + threadIdx.x;
    if (g < NE) cnt[g] = 0;
    const long nt = (long)gridDim.x * 256;
    const long N_W4 = (long)NE * H_DIM * H_DIM / 4;  // 8,388,608 float4
    const float4* w4 = (const float4*)w;
    ushort4* wb4 = (ushort4*)wb;
    for (long i = g; i < N_W4; i += nt) {
        float4 v = w4[i];
        wb4[i] = make_ushort4(f32_to_bf16(v.x), f32_to_bf16(v.y),
                              f32_to_bf16(v.z), f32_to_bf16(v.w));
    }
}

// ---------------------------------------------------------------------------
// Kernel 2: router (R0-exact). 512 blocks x 16 tokens, gate staged in LDS,
// fused X fp32->bf16, fp32 logits, softmax-free top-2, per-block aggregated
// list append.
// ---------------------------------------------------------------------------
__global__ __launch_bounds__(256) void router_kernel(
        const float* __restrict__ x, const float* __restrict__ gate,
        unsigned short* __restrict__ xb, float* __restrict__ logits,
        int* __restrict__ cnt, int* __restrict__ list, float* __restrict__ wl) {
    __shared__ float4 gs[NE * H_DIM / 4];  // 64 KiB
    __shared__ int aExp[32];
    __shared__ float aW[32];
    const float4* g4 = (const float4*)gate;
    for (int i = threadIdx.x; i < NE * H_DIM / 4; i += 256) gs[i] = g4[i];
    __syncthreads();

    const int wave = threadIdx.x >> 6, lane = threadIdx.x & 63;

    for (int it = 0; it < 4; ++it) {
        const int tok = wave * 4 + it;               // 0..15 within block
        const int t = blockIdx.x * 16 + tok;
        const float4* xr = (const float4*)(x + (long)t * H_DIM);
        ushort4* xw = (ushort4*)(xb + (long)t * H_DIM);
        float acc[NE];
#pragma unroll
        for (int e = 0; e < NE; ++e) acc[e] = 0.f;
#pragma unroll
        for (int i = 0; i < 8; ++i) {
            float4 xv = xr[i * 64 + lane];
            xw[i * 64 + lane] = make_ushort4(f32_to_bf16(xv.x), f32_to_bf16(xv.y),
                                             f32_to_bf16(xv.z), f32_to_bf16(xv.w));
#pragma unroll
            for (int e = 0; e < NE; ++e) {
                float4 gv = gs[e * 512 + i * 64 + lane];
                acc[e] += xv.x * gv.x + xv.y * gv.y + xv.z * gv.z + xv.w * gv.w;
            }
        }
#pragma unroll
        for (int e = 0; e < NE; ++e)
#pragma unroll
            for (int off = 32; off > 0; off >>= 1)
                acc[e] += __shfl_xor(acc[e], off, 64);

        if (lane == 0) {
            float l0 = -1e30f; int i0 = 0;
#pragma unroll
            for (int e = 0; e < NE; ++e)
                if (acc[e] > l0) { l0 = acc[e]; i0 = e; }
            float l1 = -1e30f; int i1 = 0;
#pragma unroll
            for (int e = 0; e < NE; ++e)
                if (e != i0 && acc[e] > l1) { l1 = acc[e]; i1 = e; }
            float e1v = __expf(l1 - l0);
            float inv = 1.f / (1.f + e1v);
#pragma unroll
            for (int e = 0; e < NE; ++e) logits[(long)t * NE + e] = acc[e];
            aExp[tok * 2] = i0;     aW[tok * 2] = inv;
            aExp[tok * 2 + 1] = i1; aW[tok * 2 + 1] = e1v * inv;
        }
    }
    __syncthreads();

    if (threadIdx.x < NE) {
        const int e = threadIdx.x;
        int c = 0;
#pragma unroll
        for (int k = 0; k < 32; ++k) c += (aExp[k] == e);
        if (c) {
            int pos = atomicAdd(&cnt[e], c);
            for (int k = 0; k < 32; ++k)
                if (aExp[k] == e) {
                    list[e * T_TOK + pos] = blockIdx.x * 16 + (k >> 1);
                    wl[e * T_TOK + pos] = aW[k];
                    ++pos;
                }
        }
    }
}

// ---------------------------------------------------------------------------
// Kernel 3: grouped expert GEMM. R0-exact EXCEPT one change (clean A/B):
// A-side double buffer + counted vmcnt. Block order, swizzle, epilogue,
// tile geometry (128x128, BK=64, 4 waves of 4x4 16x16x32 MFMA) unchanged.
//
// Schedule per K-tile t:
//   s_barrier (WAR: compute(t-1) reads retired in all waves)
//   issue 4x B(t) -> Bs            (dense, L2-hot under e-major order)
//   issue 4x A(t+1) -> As[(t+1)&1] (scattered gather; latency spans
//                                   the whole compute(t) phase)
//   s_waitcnt vmcnt(4)             (oldest 8 = A(t)+B(t) retired;
//                                   A(t+1) stays in flight -- never 0
//                                   until the last tile)
//   s_barrier; compute As[t&1], Bs
// Exposed latency/tile: one dense L2-hit B read (~250cy) instead of R0's
// full drain incl. the scattered gather (~600-900cy). R7 tested this with
// rt-major order which pushed B to HBM (FETCH 354->402MB) - confounded;
// this round isolates the schedule. LDS 49.4 KiB -> still 3 blocks/CU
// (reg-file caps at 3 waves/SIMD anyway: ~100 VGPR + 64 AGPR acc).
// ---------------------------------------------------------------------------
__global__ __launch_bounds__(256, 4) void moe_gemm(
        const unsigned short* __restrict__ xb, const unsigned short* __restrict__ wb,
        const int* __restrict__ cnt, const int* __restrict__ list,
        const float* __restrict__ wl, float* __restrict__ out) {
    __shared__ uint4 As[2][1024];  // 2 x 16 KiB (A double-buffered)
    __shared__ uint4 Bs[1024];     // 16 KiB
    __shared__ int tIdx[128];
    __shared__ float tw[128];

    const int bx = blockIdx.x;
    const int e  = bx >> 10;         // 1024 blocks per expert (e-major: R0 order)
    const int rt = (bx >> 4) & 63;   // 64 row tiles
    const int ct = bx & 15;          // 16 col tiles
    const int n = cnt[e];
    const int row0 = rt << 7;
    if (row0 >= n) return;
    const int rv = min(128, n - row0);

    const int tid = threadIdx.x;
    if (tid < 128) {
        if (tid < rv) {
            tIdx[tid] = list[e * T_TOK + row0 + tid];
            tw[tid]   = wl[e * T_TOK + row0 + tid];
        } else { tIdx[tid] = 0; tw[tid] = 0.f; }
    }
    __syncthreads();

    const int wave = tid >> 6, lane = tid & 63;
    const int wm = (wave >> 1) << 6;   // 0 / 64
    const int wn = (wave & 1) << 6;    // 0 / 64
    const int quad = lane >> 4, l16 = lane & 15;

    f32x4 acc[4][4];
#pragma unroll
    for (int i = 0; i < 4; ++i)
#pragma unroll
        for (int j = 0; j < 4; ++j) acc[i][j] = (f32x4){0.f, 0.f, 0.f, 0.f};

    // Per-lane global sources for async staging: phys chunk p = i*256+tid
    const unsigned short* aSrc[4];
    const unsigned short* bSrc[4];
    const long wbase = (long)e * H_DIM * H_DIM + (long)(ct * 128) * H_DIM;
#pragma unroll
    for (int i = 0; i < 4; ++i) {
        const int p = i * 256 + tid;
        const int r = p >> 3;
        const int c = (p & 7) ^ (r & 7);   // logical k-chunk for this phys slot
        aSrc[i] = xb + (long)tIdx[r] * H_DIM + c * 8;
        bSrc[i] = wb + wbase + (long)r * H_DIM + c * 8;
    }
    const int dst0 = wave * 64;

    // Prologue: issue A(0) into As[0] (4 loads in flight).
#pragma unroll
    for (int i = 0; i < 4; ++i) async_ld16(aSrc[i], &As[0][i * 256 + dst0]);

    for (int kt = 0; kt < NT; ++kt) {
        const int k0 = kt << 6;
        // WAR guard: all waves consumed Bs(kt-1) and As[(kt+1)&1] (parity
        // of kt-1) before restaging them.
        __builtin_amdgcn_s_barrier();

#pragma unroll
        for (int i = 0; i < 4; ++i)
            async_ld16(bSrc[i] + k0, &Bs[i * 256 + dst0]);
        if (kt + 1 < NT) {
#pragma unroll
            for (int i = 0; i < 4; ++i)
                async_ld16(aSrc[i] + k0 + 64, &As[(kt + 1) & 1][i * 256 + dst0]);
            // Outstanding: A(kt)4 (oldest) + B(kt)4 + A(kt+1)4. Wait to 4:
            // A(kt),B(kt) retired; A(kt+1) rides across compute(kt).
            asm volatile("s_waitcnt vmcnt(4)" ::: "memory");
        } else {
            asm volatile("s_waitcnt vmcnt(0)" ::: "memory");
        }
        __builtin_amdgcn_s_barrier();   // tile kt staged for all waves

        const s16x8* Ap = (const s16x8*)&As[kt & 1][0];
        const s16x8* Bp = (const s16x8*)&Bs[0];
#pragma unroll
        for (int ks = 0; ks < 2; ++ks) {
            s16x8 af[4], bfr[4];
            const int kc = ks * 4 + quad;
#pragma unroll
            for (int i = 0; i < 4; ++i) {
                int r = wm + i * 16 + l16;
                af[i] = Ap[(r << 3) | (kc ^ (r & 7))];
            }
#pragma unroll
            for (int j = 0; j < 4; ++j) {
                int d = wn + j * 16 + l16;
                bfr[j] = Bp[(d << 3) | (kc ^ (d & 7))];
            }
#pragma unroll
            for (int i = 0; i < 4; ++i)
#pragma unroll
                for (int j = 0; j < 4; ++j)
                    acc[i][j] = __builtin_amdgcn_mfma_f32_16x16x32_bf16(
                        af[i], bfr[j], acc[i][j], 0, 0, 0);
        }
    }

    // Epilogue: C/D layout col = lane&15, row = quad*4 + reg. (R0-exact)
    const int colbase = ct * 128 + wn;
#pragma unroll
    for (int i = 0; i < 4; ++i) {
        const int rbase = wm + i * 16 + quad * 4;
#pragma unroll
        for (int jr = 0; jr < 4; ++jr) {
            const int r = rbase + jr;
            if (r < rv) {
                const float wgt = tw[r];
                const long orow = (long)tIdx[r] * H_DIM + colbase;
#pragma unroll
                for (int j = 0; j < 4; ++j)
                    atomicAdd(&out[orow + j * 16 + l16], acc[i][j][jr] * wgt);
            }
        }
    }
}

// ---------------------------------------------------------------------------
extern "C" void kernel_launch(void* const* d_in, const int* in_sizes, int n_in,
                              void* d_out, int out_size, void* d_ws, size_t ws_size,
                              hipStream_t stream) {
    (void)in_sizes; (void)n_in; (void)out_size; (void)ws_size;
    const float* x    = (const float*)d_in[0];   // [T, H] fp32
    const float* gate = (const float*)d_in[1];   // [E, H] fp32
    const float* w    = (const float*)d_in[2];   // [E, H, H] fp32

    float* out    = (float*)d_out;                       // [T, H]
    float* logits = out + (size_t)T_TOK * H_DIM;         // [T, E]

    char* ws = (char*)d_ws;
    unsigned short* xb = (unsigned short*)(ws);                 // 33,554,432 B
    unsigned short* wb = (unsigned short*)(ws + 33554432);      // 67,108,864 B
    int*   cnt  = (int*)(ws + 100663296);                       // 32 B
    int*   list = (int*)(ws + 100663328);                       // 262,144 B
    float* wl   = (float*)(ws + 100925472);                     // 262,144 B

    hipMemsetAsync(out, 0, (size_t)T_TOK * H_DIM * sizeof(float), stream);
    prep_kernel<<<2048, 256, 0, stream>>>(w, wb, cnt);
    router_kernel<<<512, 256, 0, stream>>>(x, gate, xb, logits, cnt, list, wl);
    moe_gemm<<<8192, 256, 0, stream>>>(xb, wb, cnt, list, wl, out);
}

// Round 9
// 489.530 us; speedup vs baseline: 1.1494x; 1.1494x over previous
//
#include <hip/hip_runtime.h>
#include <hip/hip_bf16.h>

// Problem constants (B=4, S=2048, H=2048, E=8, K=2)
#define T_TOK 8192
#define H_DIM 2048
#define NE 8

typedef float f32x4 __attribute__((ext_vector_type(4)));
typedef short s16x8 __attribute__((ext_vector_type(8)));

typedef __attribute__((address_space(3))) unsigned int lds_uint;
typedef __attribute__((address_space(1))) const unsigned int glob_uint;

static __device__ __forceinline__ void async_ld16(const void* g, void* l) {
    // 64 lanes x 16B: global per-lane address -> LDS (wave-uniform base + lane*16)
    __builtin_amdgcn_global_load_lds((glob_uint*)g, (lds_uint*)l, 16, 0, 0);
}

static __device__ __forceinline__ unsigned short f32_to_bf16(float f) {
    unsigned int u = __builtin_bit_cast(unsigned int, f);
    unsigned int r = (u + 0x7FFFu + ((u >> 16) & 1u)) >> 16;
    return (unsigned short)r;
}

// ---------------------------------------------------------------------------
// Kernel 1: convert W fp32 -> bf16, zero expert counters.
// (out-zeroing via hipMemsetAsync; X conversion fused into router)
// ---------------------------------------------------------------------------
__global__ __launch_bounds__(256) void prep_kernel(
        const float* __restrict__ w, unsigned short* __restrict__ wb,
        int* __restrict__ cnt) {
    const long g = (long)blockIdx.x * 256 + threadIdx.x;
    if (g < NE) cnt[g] = 0;
    const long nt = (long)gridDim.x * 256;
    const long N_W4 = (long)NE * H_DIM * H_DIM / 4;  // 8,388,608 float4
    const float4* w4 = (const float4*)w;
    ushort4* wb4 = (ushort4*)wb;
    for (long i = g; i < N_W4; i += nt) {
        float4 v = w4[i];
        wb4[i] = make_ushort4(f32_to_bf16(v.x), f32_to_bf16(v.y),
                              f32_to_bf16(v.z), f32_to_bf16(v.w));
    }
}

// ---------------------------------------------------------------------------
// Kernel 2: router. 512 blocks x 16 tokens. Per wave: 4 tokens, fused
// fp32->bf16 X conversion. fp32 logits (exact), softmax-free top-2,
// per-block aggregated list append (8 atomics/block instead of 32).
// ---------------------------------------------------------------------------
__global__ __launch_bounds__(256) void router_kernel(
        const float* __restrict__ x, const float* __restrict__ gate,
        unsigned short* __restrict__ xb, float* __restrict__ logits,
        int* __restrict__ cnt, int* __restrict__ list, float* __restrict__ wl) {
    __shared__ float4 gs[NE * H_DIM / 4];  // 64 KiB
    __shared__ int aExp[32];
    __shared__ float aW[32];
    const float4* g4 = (const float4*)gate;
    for (int i = threadIdx.x; i < NE * H_DIM / 4; i += 256) gs[i] = g4[i];
    __syncthreads();

    const int wave = threadIdx.x >> 6, lane = threadIdx.x & 63;

    for (int it = 0; it < 4; ++it) {
        const int tok = wave * 4 + it;               // 0..15 within block
        const int t = blockIdx.x * 16 + tok;
        const float4* xr = (const float4*)(x + (long)t * H_DIM);
        ushort4* xw = (ushort4*)(xb + (long)t * H_DIM);
        float acc[NE];
#pragma unroll
        for (int e = 0; e < NE; ++e) acc[e] = 0.f;
#pragma unroll
        for (int i = 0; i < 8; ++i) {
            float4 xv = xr[i * 64 + lane];
            xw[i * 64 + lane] = make_ushort4(f32_to_bf16(xv.x), f32_to_bf16(xv.y),
                                             f32_to_bf16(xv.z), f32_to_bf16(xv.w));
#pragma unroll
            for (int e = 0; e < NE; ++e) {
                float4 gv = gs[e * 512 + i * 64 + lane];
                acc[e] += xv.x * gv.x + xv.y * gv.y + xv.z * gv.z + xv.w * gv.w;
            }
        }
#pragma unroll
        for (int e = 0; e < NE; ++e)
#pragma unroll
            for (int off = 32; off > 0; off >>= 1)
                acc[e] += __shfl_xor(acc[e], off, 64);

        if (lane == 0) {
            float l0 = -1e30f; int i0 = 0;
#pragma unroll
            for (int e = 0; e < NE; ++e)
                if (acc[e] > l0) { l0 = acc[e]; i0 = e; }
            float l1 = -1e30f; int i1 = 0;
#pragma unroll
            for (int e = 0; e < NE; ++e)
                if (e != i0 && acc[e] > l1) { l1 = acc[e]; i1 = e; }
            float e1v = __expf(l1 - l0);
            float inv = 1.f / (1.f + e1v);
#pragma unroll
            for (int e = 0; e < NE; ++e) logits[(long)t * NE + e] = acc[e];
            aExp[tok * 2] = i0;     aW[tok * 2] = inv;
            aExp[tok * 2 + 1] = i1; aW[tok * 2 + 1] = e1v * inv;
        }
    }
    __syncthreads();

    if (threadIdx.x < NE) {
        const int e = threadIdx.x;
        int c = 0;
#pragma unroll
        for (int k = 0; k < 32; ++k) c += (aExp[k] == e);
        if (c) {
            int pos = atomicAdd(&cnt[e], c);
            for (int k = 0; k < 32; ++k)
                if (aExp[k] == e) {
                    list[e * T_TOK + pos] = blockIdx.x * 16 + (k >> 1);
                    wl[e * T_TOK + pos] = aW[k];
                    ++pos;
                }
        }
    }
}

// ---------------------------------------------------------------------------
// Kernel 3: grouped expert GEMM, async staging. Per expert e: Y = gather(X)
// @ W_e^T, scaled by token weight, atomicAdd into out. 128x128 tile, BK=64,
// 4 waves of 4x4 16x16x32 bf16 MFMA. LDS layout XOR-swizzled: logical (row r,
// 16B-chunk c) lives at phys chunk (r<<3)|(c^(r&7)). global_load_lds writes
// phys-linear (wave base + lane*16), so each lane fetches the global column
// for its phys slot: c_log = (p&7)^(r&7) (involution). ds_read_b128 of a
// k-column then hits 2-way-max bank aliasing (free).
//
// SESSION LEDGER (why this exact structure): R1 256²/4-phase=634us (VGPR cap
// spill + 1blk/CU packing); R2 dbuf-both+vmcnt=230 (occupancy -2blk); R6
// fused W-cvt=305 (VALU poisons MFMA); R7 A-dbuf rt-major=272 (B->HBM);
// R8 A-dbuf e-major=288 (occupancy+VALU; FETCH even dropped). 3-4 blocks/CU
// of TLP already hide the staging latency; every pipelining graft that costs
// LDS/VGPR loses more TLP than it buys. This minimal 2-barrier form is the
// measured optimum (205-208us).
// ---------------------------------------------------------------------------
__global__ __launch_bounds__(256, 4) void moe_gemm(
        const unsigned short* __restrict__ xb, const unsigned short* __restrict__ wb,
        const int* __restrict__ cnt, const int* __restrict__ list,
        const float* __restrict__ wl, float* __restrict__ out) {
    __shared__ uint4 As[1024];  // 128 rows x 64 bf16 = 16 KiB
    __shared__ uint4 Bs[1024];
    __shared__ int tIdx[128];
    __shared__ float tw[128];

    const int bx = blockIdx.x;
    const int e  = bx >> 10;         // 1024 blocks per expert
    const int rt = (bx >> 4) & 63;   // 64 row tiles
    const int ct = bx & 15;          // 16 col tiles
    const int n = cnt[e];
    const int row0 = rt << 7;
    if (row0 >= n) return;
    const int rv = min(128, n - row0);

    const int tid = threadIdx.x;
    if (tid < 128) {
        if (tid < rv) {
            tIdx[tid] = list[e * T_TOK + row0 + tid];
            tw[tid]   = wl[e * T_TOK + row0 + tid];
        } else { tIdx[tid] = 0; tw[tid] = 0.f; }
    }
    __syncthreads();

    const int wave = tid >> 6, lane = tid & 63;
    const int wm = (wave >> 1) << 6;   // 0 / 64
    const int wn = (wave & 1) << 6;    // 0 / 64
    const int quad = lane >> 4, l16 = lane & 15;

    f32x4 acc[4][4];
#pragma unroll
    for (int i = 0; i < 4; ++i)
#pragma unroll
        for (int j = 0; j < 4; ++j) acc[i][j] = (f32x4){0.f, 0.f, 0.f, 0.f};

    // Per-lane global sources for async staging: phys chunk p = i*256+wave*64+lane
    const unsigned short* aSrc[4];
    const unsigned short* bSrc[4];
    const long wbase = (long)e * H_DIM * H_DIM + (long)(ct * 128) * H_DIM;
#pragma unroll
    for (int i = 0; i < 4; ++i) {
        const int p = i * 256 + wave * 64 + lane;
        const int r = p >> 3;
        const int c = (p & 7) ^ (r & 7);   // logical k-chunk for this phys slot
        aSrc[i] = xb + (long)tIdx[r] * H_DIM + c * 8;
        bSrc[i] = wb + wbase + (long)r * H_DIM + c * 8;
    }

    for (int kt = 0; kt < H_DIM / 64; ++kt) {
        const int k0 = kt * 64;
#pragma unroll
        for (int i = 0; i < 4; ++i) {
            async_ld16(aSrc[i] + k0, &As[i * 256 + wave * 64]);
            async_ld16(bSrc[i] + k0, &Bs[i * 256 + wave * 64]);
        }
        __syncthreads();
#pragma unroll
        for (int ks = 0; ks < 2; ++ks) {
            s16x8 af[4], bfr[4];
            const int kc = ks * 4 + quad;
#pragma unroll
            for (int i = 0; i < 4; ++i) {
                int r = wm + i * 16 + l16;
                af[i] = ((const s16x8*)As)[(r << 3) | (kc ^ (r & 7))];
            }
#pragma unroll
            for (int j = 0; j < 4; ++j) {
                int d = wn + j * 16 + l16;
                bfr[j] = ((const s16x8*)Bs)[(d << 3) | (kc ^ (d & 7))];
            }
#pragma unroll
            for (int i = 0; i < 4; ++i)
#pragma unroll
                for (int j = 0; j < 4; ++j)
                    acc[i][j] = __builtin_amdgcn_mfma_f32_16x16x32_bf16(
                        af[i], bfr[j], acc[i][j], 0, 0, 0);
        }
        __syncthreads();
    }

    // Epilogue: C/D layout col = lane&15, row = quad*4 + reg.
    const int colbase = ct * 128 + wn;
#pragma unroll
    for (int i = 0; i < 4; ++i) {
        const int rbase = wm + i * 16 + quad * 4;
#pragma unroll
        for (int jr = 0; jr < 4; ++jr) {
            const int r = rbase + jr;
            if (r < rv) {
                const float wgt = tw[r];
                const long orow = (long)tIdx[r] * H_DIM + colbase;
#pragma unroll
                for (int j = 0; j < 4; ++j)
                    atomicAdd(&out[orow + j * 16 + l16], acc[i][j][jr] * wgt);
            }
        }
    }
}

// ---------------------------------------------------------------------------
extern "C" void kernel_launch(void* const* d_in, const int* in_sizes, int n_in,
                              void* d_out, int out_size, void* d_ws, size_t ws_size,
                              hipStream_t stream) {
    (void)in_sizes; (void)n_in; (void)out_size; (void)ws_size;
    const float* x    = (const float*)d_in[0];   // [T, H] fp32
    const float* gate = (const float*)d_in[1];   // [E, H] fp32
    const float* w    = (const float*)d_in[2];   // [E, H, H] fp32

    float* out    = (float*)d_out;                       // [T, H]
    float* logits = out + (size_t)T_TOK * H_DIM;         // [T, E]

    char* ws = (char*)d_ws;
    unsigned short* xb = (unsigned short*)(ws);                 // 33,554,432 B
    unsigned short* wb = (unsigned short*)(ws + 33554432);      // 67,108,864 B
    int*   cnt  = (int*)(ws + 100663296);                       // 32 B
    int*   list = (int*)(ws + 100663328);                       // 262,144 B
    float* wl   = (float*)(ws + 100925472);                     // 262,144 B

    hipMemsetAsync(out, 0, (size_t)T_TOK * H_DIM * sizeof(float), stream);
    prep_kernel<<<2048, 256, 0, stream>>>(w, wb, cnt);
    router_kernel<<<512, 256, 0, stream>>>(x, gate, xb, logits, cnt, list, wl);
    moe_gemm<<<8192, 256, 0, stream>>>(xb, wb, cnt, list, wl, out);
}